// Round 16
// baseline (559.915 us; speedup 1.0000x reference)
//
#include <hip/hip_runtime.h>
#include <math.h>
#include <stdint.h>

#define Bn 32
#define Sn 512
#define Dn 768
#define Hn 8
#define DKn 96
#define Pn 3

typedef __bf16 bf16_t;
typedef bf16_t bf16x8 __attribute__((ext_vector_type(8)));
typedef float f32x4 __attribute__((ext_vector_type(4)));

__device__ __forceinline__ bf16_t f2bf(float f) { return (bf16_t)f; }

__device__ __forceinline__ void gload16(const void* g, void* l) {
    __builtin_amdgcn_global_load_lds((const __attribute__((address_space(1))) void*)g,
                                     (__attribute__((address_space(3))) void*)l, 16, 0, 0);
}

// ---------------- block reduction helpers (blockDim == 256) ----------------
__device__ __forceinline__ float brsum(float v, float* red) {
    int t = threadIdx.x;
    red[t] = v; __syncthreads();
    #pragma unroll
    for (int o = 128; o > 0; o >>= 1) {
        if (t < o) red[t] += red[t + o];
        __syncthreads();
    }
    float r = red[0]; __syncthreads();
    return r;
}

// ---------------- LayerNorm -> bf16 (torch-style: unbiased var, eps on std) -------------
__global__ __launch_bounds__(256) void ln_kernel(const float* __restrict__ in,
                                                 const float* __restrict__ ga,
                                                 const float* __restrict__ gb,
                                                 bf16_t* __restrict__ out) {
    __shared__ float red[256];
    long row = blockIdx.x;
    const float* x = in + row * Dn;
    bf16_t* y = out + row * Dn;
    int t = threadIdx.x;
    float v0 = x[t], v1 = x[t + 256], v2 = x[t + 512];
    float mean = brsum(v0 + v1 + v2, red) / (float)Dn;
    float d0 = v0 - mean, d1 = v1 - mean, d2 = v2 - mean;
    float ss = brsum(d0 * d0 + d1 * d1 + d2 * d2, red);
    float inv = 1.0f / (sqrtf(ss / (float)(Dn - 1)) + 1e-6f);
    y[t]       = f2bf(ga[t]       * d0 * inv + gb[t]);
    y[t + 256] = f2bf(ga[t + 256] * d1 * inv + gb[t + 256]);
    y[t + 512] = f2bf(ga[t + 512] * d2 * inv + gb[t + 512]);
}

// ---------------- fp32 -> bf16 weight conversion (8 matrices of Dn x Dn) -----------------
__global__ __launch_bounds__(256) void cvt8(const float* __restrict__ s0,
                                            const float* __restrict__ s1,
                                            const float* __restrict__ s2,
                                            const float* __restrict__ s3,
                                            const float* __restrict__ s4,
                                            const float* __restrict__ s5,
                                            const float* __restrict__ s6,
                                            const float* __restrict__ s7,
                                            bf16_t* __restrict__ dst) {
    int y = blockIdx.y;
    const float* s = (y == 0) ? s0 : (y == 1) ? s1 : (y == 2) ? s2 : (y == 3) ? s3
                   : (y == 4) ? s4 : (y == 5) ? s5 : (y == 6) ? s6 : s7;
    long i = (long)blockIdx.x * 1024 + threadIdx.x * 4;
    float4 v = *reinterpret_cast<const float4*>(s + i);
    bf16_t* d = dst + (long)y * Dn * Dn + i;
    d[0] = f2bf(v.x); d[1] = f2bf(v.y); d[2] = f2bf(v.z); d[3] = f2bf(v.w);
}

// ---------------- bias concat: 8 segments of 768 floats ----------------
__global__ __launch_bounds__(256) void biascat_k(const float* __restrict__ s0,
                                                 const float* __restrict__ s1,
                                                 const float* __restrict__ s2,
                                                 const float* __restrict__ s3,
                                                 const float* __restrict__ s4,
                                                 const float* __restrict__ s5,
                                                 const float* __restrict__ s6,
                                                 const float* __restrict__ s7,
                                                 float* __restrict__ dst) {
    int y = blockIdx.x;
    const float* s = (y == 0) ? s0 : (y == 1) ? s1 : (y == 2) ? s2 : (y == 3) ? s3
                   : (y == 4) ? s4 : (y == 5) ? s5 : (y == 6) ? s6 : s7;
    for (int i = threadIdx.x; i < Dn; i += 256) dst[(long)y * Dn + i] = s[i];
}

__global__ void zero_kernel(float* p, int n) {
    int i = blockIdx.x * 256 + threadIdx.x;
    if (i < n) p[i] = 0.0f;
}

// =========================================================================================
// gemm_bt: bf16 MFMA NT GEMM, 128x128 tile, 4 waves, BK=32, global_load_lds staging.
// FRAGMENT-LINEAR LDS (this round): chunk c (16 rows x 32 k) granule l holds
// A[c*16 + (l&15)][(l>>4)*8..+8] -> fragment read is 64 consecutive granules per wave
// (conflict-free, proven by gemm256's identical layout measuring 0 conflicts). Same
// logical lane->(row,k) mapping as before; math identical.
// =========================================================================================
template <int EPI>
__global__ __launch_bounds__(256) void gemm_bt(
    const bf16_t* __restrict__ Ag, const bf16_t* __restrict__ Bg,
    bf16_t* __restrict__ Cg, float* __restrict__ outv,
    int lda, int ldb, int ldc, int K,
    long sAhi, long sAlo, long sBhi, long sBlo, long sChi, long sClo,
    int lgZ, float alpha,
    const float* __restrict__ bias, long bias_zs,
    const float* __restrict__ denom,
    const float* __restrict__ aspw) {
    __shared__ __align__(16) bf16_t As[128 * 32];
    __shared__ __align__(16) bf16_t Bs[128 * 32];

    unsigned gx = gridDim.x, gy = gridDim.y;
    unsigned nwg = gx * gy * gridDim.z;
    unsigned flat = (blockIdx.z * gy + blockIdx.y) * gx + blockIdx.x;
    unsigned q8 = nwg >> 3, r8 = nwg & 7;
    unsigned xcd = flat & 7, idx = flat >> 3;
    unsigned swz = (xcd < r8 ? xcd * (q8 + 1) : r8 * (q8 + 1) + (xcd - r8) * q8) + idx;
    unsigned bx = swz % gx;
    unsigned rest = swz / gx;
    unsigned by = rest % gy;
    unsigned zz = rest / gy;
    int zb = zz >> lgZ;
    int zg = zz & ((1 << lgZ) - 1);
    long zful = zz;

    const bf16_t* A = Ag + zb * sAhi + zg * sAlo;
    const bf16_t* B = Bg + zb * sBhi + zg * sBlo;

    int n0 = bx * 128;
    int m0 = by * 128;
    int tid = threadIdx.x;
    int lane = tid & 63, wv = tid >> 6;
    int wm = wv >> 1, wn = wv & 1;

    // fragment-linear staging: granule l of chunk <- row (l&15), k-part (l>>4)*8
    int srow = lane & 15;
    int skc = (lane >> 4) * 8;
    const bf16_t* pA0 = A + (size_t)(m0 + wv * 16 + srow) * lda + skc;
    const bf16_t* pA1 = pA0 + (size_t)64 * lda;
    const bf16_t* pB0 = B + (size_t)(n0 + wv * 16 + srow) * ldb + skc;
    const bf16_t* pB1 = pB0 + (size_t)64 * ldb;
    bf16_t* lA0 = As + wv * 512 + lane * 8;
    bf16_t* lA1 = As + (4 + wv) * 512 + lane * 8;
    bf16_t* lB0 = Bs + wv * 512 + lane * 8;
    bf16_t* lB1 = Bs + (4 + wv) * 512 + lane * 8;

    f32x4 acc[4][4];
    #pragma unroll
    for (int i = 0; i < 4; i++)
        #pragma unroll
        for (int j = 0; j < 4; j++) acc[i][j] = (f32x4){0.f, 0.f, 0.f, 0.f};

    // fragment read: wave wm reads chunks wm*4..wm*4+3, granule = lane (consecutive)
    const bf16_t* ar = As + (wm * 4) * 512 + lane * 8;
    const bf16_t* br = Bs + (wn * 4) * 512 + lane * 8;

    for (int k0 = 0; k0 < K; k0 += 32) {
        gload16(pA0 + k0, lA0);
        gload16(pA1 + k0, lA1);
        gload16(pB0 + k0, lB0);
        gload16(pB1 + k0, lB1);
        __syncthreads();
        bf16x8 a[4], b[4];
        #pragma unroll
        for (int i = 0; i < 4; i++) a[i] = *(const bf16x8*)(ar + i * 512);
        #pragma unroll
        for (int j = 0; j < 4; j++) b[j] = *(const bf16x8*)(br + j * 512);
        #pragma unroll
        for (int i = 0; i < 4; i++)
            #pragma unroll
            for (int j = 0; j < 4; j++)
                acc[i][j] = __builtin_amdgcn_mfma_f32_16x16x32_bf16(a[i], b[j], acc[i][j], 0, 0, 0);
        __syncthreads();
    }

    int nb = n0 + wn * 64 + (lane & 15);
    int mbase = m0 + wm * 64 + (lane >> 4) * 4;
    const float* bz = bias ? bias + zb * bias_zs : nullptr;

    if (EPI == 0) {
        bf16_t* Cz = Cg + zb * sChi + zg * sClo;
        #pragma unroll
        for (int i = 0; i < 4; i++) {
            #pragma unroll
            for (int r = 0; r < 4; r++) {
                long m = mbase + i * 16 + r;
                bf16_t* crow = Cz + m * (long)ldc;
                #pragma unroll
                for (int j = 0; j < 4; j++) {
                    int col = nb + j * 16;
                    float v = acc[i][j][r] * alpha;
                    if (bz) v += bz[col];
                    crow[col] = f2bf(v);
                }
            }
        }
    } else if (EPI == 1) {
        bf16_t* Cz = Cg + zb * sChi + zg * sClo;
        const float* dz = denom + zful * Sn;
        #pragma unroll
        for (int i = 0; i < 4; i++) {
            #pragma unroll
            for (int r = 0; r < 4; r++) {
                int m = mbase + i * 16 + r;
                float dinv = 1.0f / dz[m];
                bf16_t* crow = Cz + (long)m * ldc;
                #pragma unroll
                for (int j = 0; j < 4; j++) {
                    float v = fmaxf((acc[i][j][r] + bz[nb + j * 16]) * dinv, 0.0f);
                    crow[nb + j * 16] = f2bf(v);
                }
            }
        }
    } else {  // EPI == 2
        const float* dz = denom + zful * Sn;
        float csum[4] = {0.f, 0.f, 0.f, 0.f};
        #pragma unroll
        for (int i = 0; i < 4; i++) {
            #pragma unroll
            for (int r = 0; r < 4; r++) {
                int m = mbase + i * 16 + r;
                float dinv = 1.0f / dz[m];
                float wgt = (aspw && zb) ? aspw[(long)zg * Sn + m] : 1.0f;
                #pragma unroll
                for (int j = 0; j < 4; j++) {
                    float v = fmaxf((acc[i][j][r] + bz[nb + j * 16]) * dinv, 0.0f);
                    csum[j] += v * wgt;
                }
            }
        }
        #pragma unroll
        for (int j = 0; j < 4; j++) {
            float s = csum[j];
            s += __shfl_xor(s, 16);
            s += __shfl_xor(s, 32);
            if (lane < 16) atomicAdd(&outv[zful * Dn + nb + j * 16], s);
        }
    }
}

// =========================================================================================
// gemm256: 256x128 tile, BK=32, 8 waves (4m x 2n, wave-tile 64x64, acc 4x4 = 64 regs),
// 3-buffer LDS (72 KB) with 2-tile-ahead staging and counted vmcnt(3); 2 blocks/CU.
// =========================================================================================
#define CH 24   // 16 A-chunks + 8 B-chunks, each 512 elems (16 rows x 32 k)
template <int EPI>
__global__ __launch_bounds__(512, 4) void gemm256(
    const bf16_t* __restrict__ Ag, const bf16_t* __restrict__ Bg,
    bf16_t* __restrict__ Cg, float* __restrict__ outv,
    int lda, int ldb, int ldc, int K,
    long sAhi, long sAlo, long sBhi, long sBlo, long sChi, long sClo,
    int lgZ,
    const float* __restrict__ bias, long bias_zs,
    const float* __restrict__ denom,
    const float* __restrict__ aspw) {
    __shared__ __align__(16) bf16_t lds[3][CH * 512];   // 72 KiB

    unsigned gx = gridDim.x, gy = gridDim.y;
    unsigned nwg = gx * gy * gridDim.z;
    unsigned flat = (blockIdx.z * gy + blockIdx.y) * gx + blockIdx.x;
    unsigned q8 = nwg >> 3, r8 = nwg & 7;
    unsigned xcd = flat & 7, idx = flat >> 3;
    unsigned swz = (xcd < r8 ? xcd * (q8 + 1) : r8 * (q8 + 1) + (xcd - r8) * q8) + idx;
    unsigned bx = swz % gx;
    unsigned rest = swz / gx;
    unsigned by = rest % gy;
    unsigned zz = rest / gy;
    int zb = zz >> lgZ;
    int zg = zz & ((1 << lgZ) - 1);
    long zful = zz;

    const bf16_t* A = Ag + zb * sAhi + zg * sAlo;
    const bf16_t* B = Bg + zb * sBhi + zg * sBlo;

    int n0 = bx * 128, m0 = by * 256;
    int tid = threadIdx.x;
    int lane = tid & 63, w = tid >> 6;
    int wm = w >> 1, wn = w & 1;

    const int NT = K >> 5;

    int srowl = lane & 15;
    int skc = (lane >> 4) * 8;
    const bf16_t* src[3];
    int loff[3];
    #pragma unroll
    for (int p = 0; p < 3; ++p) {
        int ch = w * 3 + p;
        src[p] = (ch < 16) ? (A + (size_t)(m0 + ch * 16 + srowl) * lda + skc)
                           : (B + (size_t)(n0 + (ch - 16) * 16 + srowl) * ldb + skc);
        loff[p] = ch * 512 + lane * 8;
    }

    f32x4 acc[4][4];
    #pragma unroll
    for (int i = 0; i < 4; ++i)
        #pragma unroll
        for (int j = 0; j < 4; ++j) acc[i][j] = (f32x4){0.f, 0.f, 0.f, 0.f};

    #pragma unroll
    for (int p = 0; p < 3; ++p) gload16(src[p], &lds[0][loff[p]]);
    if (NT > 1) {
        #pragma unroll
        for (int p = 0; p < 3; ++p) gload16(src[p] + 32, &lds[1][loff[p]]);
        asm volatile("s_waitcnt vmcnt(3)" ::: "memory");
    } else {
        asm volatile("s_waitcnt vmcnt(0)" ::: "memory");
    }
    __builtin_amdgcn_s_barrier();

    int aoff = (wm * 4) * 512 + lane * 8;
    int boff = (16 + wn * 4) * 512 + lane * 8;

    for (int t = 0; t < NT; ++t) {
        const bf16_t* buf = &lds[t % 3][0];
        if (t + 2 < NT) {
            bf16_t* dst = &lds[(t + 2) % 3][0];
            #pragma unroll
            for (int p = 0; p < 3; ++p) gload16(src[p] + (t + 2) * 32, dst + loff[p]);
        }
        bf16x8 a[4], b[4];
        #pragma unroll
        for (int i = 0; i < 4; ++i) a[i] = *(const bf16x8*)(buf + aoff + i * 512);
        #pragma unroll
        for (int j = 0; j < 4; ++j) b[j] = *(const bf16x8*)(buf + boff + j * 512);
        asm volatile("s_waitcnt lgkmcnt(0)" ::: "memory");
        __builtin_amdgcn_sched_barrier(0);
        __builtin_amdgcn_s_setprio(1);
        #pragma unroll
        for (int i = 0; i < 4; ++i)
            #pragma unroll
            for (int j = 0; j < 4; ++j)
                acc[i][j] = __builtin_amdgcn_mfma_f32_16x16x32_bf16(a[i], b[j], acc[i][j], 0, 0, 0);
        __builtin_amdgcn_s_setprio(0);
        if (t + 2 < NT) asm volatile("s_waitcnt vmcnt(3)" ::: "memory");
        else            asm volatile("s_waitcnt vmcnt(0)" ::: "memory");
        __builtin_amdgcn_s_barrier();
    }

    int nb = n0 + wn * 64 + (lane & 15);
    int mbase = m0 + wm * 64 + (lane >> 4) * 4;
    const float* bz = bias ? bias + zb * bias_zs : nullptr;

    if (EPI == 0) {
        bf16_t* Cz = Cg + zb * sChi + zg * sClo;
        #pragma unroll
        for (int i = 0; i < 4; ++i) {
            #pragma unroll
            for (int r = 0; r < 4; ++r) {
                long m = mbase + i * 16 + r;
                bf16_t* crow = Cz + m * (long)ldc;
                #pragma unroll
                for (int j = 0; j < 4; ++j) {
                    int col = nb + j * 16;
                    float v = acc[i][j][r];
                    if (bz) v += bz[col];
                    crow[col] = f2bf(v);
                }
            }
        }
    }
}

// =========================================================================================
// fused_adj (v2 + pad100): adj = mean_h softmax(mask(Q_h K_h^T/sqrt(dk))) + diag/mask/denom
// =========================================================================================
#define KPAD 100
__global__ __launch_bounds__(256) void fused_adj(
    const bf16_t* __restrict__ QK, bf16_t* __restrict__ adjb,
    float* __restrict__ denomv, const int* __restrict__ mask) {
    __shared__ __align__(16) bf16_t Ks[2][128 * KPAD];
    __shared__ float red[4][16];

    int L = blockIdx.x;
    int swzi = (L & 7) * 128 + (L >> 3);   // 1024 blocks, 8 XCDs x 128
    int brc = swzi >> 9;
    int rem = swzi & 511;
    int b = rem >> 4;
    int q0 = (rem & 15) * 32;

    int tid = threadIdx.x;
    int lane = tid & 63, w = tid >> 6;
    int mt = w >> 1, nh = w & 1;
    int g = lane >> 4, c = lane & 15;

    const int LDQ = 3072;
    const bf16_t* Qrow  = QK + ((long)b * Sn + q0 + mt * 16 + c) * LDQ + brc * 1536;
    const bf16_t* Kbase = QK + (long)b * Sn * LDQ + brc * 1536 + Dn;

    const int* mrow = mask + (long)b * Sn;
    unsigned mbits = 0;
    #pragma unroll
    for (int t = 0; t < 4; ++t)
        #pragma unroll
        for (int nj = 0; nj < 4; ++nj)
            if (mrow[t * 128 + nh * 64 + nj * 16 + c] != 0) mbits |= 1u << (t * 4 + nj);

    int srow[6], scc[6];
    #pragma unroll
    for (int p = 0; p < 6; ++p) { int gr = tid + p * 256; srow[p] = gr / 12; scc[p] = gr % 12; }

    f32x4 adjacc[4][4];
    #pragma unroll
    for (int t = 0; t < 4; ++t)
        #pragma unroll
        for (int nj = 0; nj < 4; ++nj) adjacc[t][nj] = (f32x4){0.f, 0.f, 0.f, 0.f};

    f32x4 S[4][4];
    bf16x8 kr0[6], kr1[6], aq[3], aqn[3];
    const float sal = 0.102062072615966f;  // 1/sqrt(96)

    // prologue: tile0 -> kr0 -> Ks[0]; tile1 -> kr1; Q head 0 -> aq
    #pragma unroll
    for (int p = 0; p < 6; ++p)
        kr0[p] = *(const bf16x8*)(Kbase + (long)srow[p] * LDQ + scc[p] * 8);
    #pragma unroll
    for (int ks = 0; ks < 3; ++ks)
        aq[ks] = *(const bf16x8*)(Qrow + ks * 32 + g * 8);
    #pragma unroll
    for (int p = 0; p < 6; ++p)
        *(bf16x8*)(&Ks[0][srow[p] * KPAD + scc[p] * 8]) = kr0[p];
    #pragma unroll
    for (int p = 0; p < 6; ++p)
        kr1[p] = *(const bf16x8*)(Kbase + (long)(128 + srow[p]) * LDQ + scc[p] * 8);
    __syncthreads();

    for (int h = 0; h < Hn; ++h) {
        #pragma unroll
        for (int t = 0; t < 4; ++t)
            #pragma unroll
            for (int nj = 0; nj < 4; ++nj) S[t][nj] = (f32x4){0.f, 0.f, 0.f, 0.f};

        float rs[4];
        #pragma unroll
        for (int t = 0; t < 4; ++t) {
            int it = h * 4 + t;
            if (it + 2 < 32) {
                int nt = it + 2;
                const bf16_t* kp = Kbase + (long)((nt & 3) * 128) * LDQ + (nt >> 2) * 96;
                if ((t & 1) == 0) {
                    #pragma unroll
                    for (int p = 0; p < 6; ++p)
                        kr0[p] = *(const bf16x8*)(kp + (long)srow[p] * LDQ + scc[p] * 8);
                } else {
                    #pragma unroll
                    for (int p = 0; p < 6; ++p)
                        kr1[p] = *(const bf16x8*)(kp + (long)srow[p] * LDQ + scc[p] * 8);
                }
            }
            if (t == 2 && h < 7) {
                #pragma unroll
                for (int ks = 0; ks < 3; ++ks)
                    aqn[ks] = *(const bf16x8*)(Qrow + (h + 1) * 96 + ks * 32 + g * 8);
            }
            #pragma unroll
            for (int nj = 0; nj < 4; ++nj) {
                #pragma unroll
                for (int ks = 0; ks < 3; ++ks) {
                    bf16x8 bk = *(const bf16x8*)(&Ks[t & 1][(nh * 64 + nj * 16 + c) * KPAD + ks * 32 + g * 8]);
                    S[t][nj] = __builtin_amdgcn_mfma_f32_16x16x32_bf16(aq[ks], bk, S[t][nj], 0, 0, 0);
                }
            }
            if (t == 3) {
                rs[0] = rs[1] = rs[2] = rs[3] = 0.f;
                #pragma unroll
                for (int tt = 0; tt < 4; ++tt)
                    #pragma unroll
                    for (int nj = 0; nj < 4; ++nj) {
                        float mkf = ((mbits >> (tt * 4 + nj)) & 1u) ? 1.0f : 0.0f;
                        #pragma unroll
                        for (int ri = 0; ri < 4; ++ri) {
                            float e = mkf * __expf(S[tt][nj][ri] * sal);
                            S[tt][nj][ri] = e;
                            rs[ri] += e;
                        }
                    }
                #pragma unroll
                for (int ri = 0; ri < 4; ++ri) {
                    rs[ri] += __shfl_xor(rs[ri], 1);
                    rs[ri] += __shfl_xor(rs[ri], 2);
                    rs[ri] += __shfl_xor(rs[ri], 4);
                    rs[ri] += __shfl_xor(rs[ri], 8);
                }
                if (c == 0) {
                    #pragma unroll
                    for (int ri = 0; ri < 4; ++ri) red[w][g * 4 + ri] = rs[ri];
                }
            }
            if (it + 1 < 32) {
                if ((t & 1) == 0) {
                    #pragma unroll
                    for (int p = 0; p < 6; ++p)
                        *(bf16x8*)(&Ks[1][srow[p] * KPAD + scc[p] * 8]) = kr1[p];
                } else {
                    #pragma unroll
                    for (int p = 0; p < 6; ++p)
                        *(bf16x8*)(&Ks[0][srow[p] * KPAD + scc[p] * 8]) = kr0[p];
                }
            }
            __syncthreads();
            if (t == 3) {
                float inv[4];
                #pragma unroll
                for (int ri = 0; ri < 4; ++ri)
                    inv[ri] = 0.125f / (red[w][g * 4 + ri] + red[w ^ 1][g * 4 + ri]);
                #pragma unroll
                for (int tt = 0; tt < 4; ++tt)
                    #pragma unroll
                    for (int nj = 0; nj < 4; ++nj)
                        #pragma unroll
                        for (int ri = 0; ri < 4; ++ri)
                            adjacc[tt][nj][ri] += S[tt][nj][ri] * inv[ri];
                if (h < 7) {
                    #pragma unroll
                    for (int ks = 0; ks < 3; ++ks) aq[ks] = aqn[ks];
                }
            }
        }
    }

    // finalize: diag=1, row-mask, rowsum -> denom
    float rm[4];
    #pragma unroll
    for (int ri = 0; ri < 4; ++ri)
        rm[ri] = (mrow[q0 + mt * 16 + g * 4 + ri] != 0) ? 1.0f : 0.0f;
    float rs2[4] = {0.f, 0.f, 0.f, 0.f};
    #pragma unroll
    for (int t = 0; t < 4; ++t)
        #pragma unroll
        for (int nj = 0; nj < 4; ++nj) {
            int n = t * 128 + nh * 64 + nj * 16 + c;
            #pragma unroll
            for (int ri = 0; ri < 4; ++ri) {
                float v = adjacc[t][nj][ri];
                int q = q0 + mt * 16 + g * 4 + ri;
                if (n == q) v = 1.0f;
                v *= rm[ri];
                adjacc[t][nj][ri] = v;
                rs2[ri] += v;
            }
        }
    #pragma unroll
    for (int ri = 0; ri < 4; ++ri) {
        rs2[ri] += __shfl_xor(rs2[ri], 1);
        rs2[ri] += __shfl_xor(rs2[ri], 2);
        rs2[ri] += __shfl_xor(rs2[ri], 4);
        rs2[ri] += __shfl_xor(rs2[ri], 8);
    }
    __syncthreads();   // all part-2 red reads done before overwrite (WAR)
    if (c == 0) {
        #pragma unroll
        for (int ri = 0; ri < 4; ++ri) red[w][g * 4 + ri] = rs2[ri];
    }
    __syncthreads();
    long zful = (long)brc * Bn + b;
    if (nh == 0 && c == 0) {
        #pragma unroll
        for (int ri = 0; ri < 4; ++ri)
            denomv[zful * Sn + q0 + mt * 16 + g * 4 + ri] =
                red[w][g * 4 + ri] + red[w ^ 1][g * 4 + ri] + 1.0f;
    }
    // stage adj tile (reuse Ks) as bf16 [32][520], then coalesced write
    bf16_t* stg = &Ks[0][0];
    #pragma unroll
    for (int t = 0; t < 4; ++t)
        #pragma unroll
        for (int nj = 0; nj < 4; ++nj) {
            int n = t * 128 + nh * 64 + nj * 16 + c;
            #pragma unroll
            for (int ri = 0; ri < 4; ++ri)
                stg[(mt * 16 + g * 4 + ri) * 520 + n] = f2bf(adjacc[t][nj][ri]);
        }
    __syncthreads();
    bf16_t* arow = adjb + (zful * Sn + q0) * Sn;
    #pragma unroll
    for (int p = 0; p < 8; ++p) {
        int gr = tid + p * 256;
        int row = gr >> 6, cc = gr & 63;
        *(bf16x8*)(arow + (long)row * Sn + cc * 8) = *(const bf16x8*)(stg + row * 520 + cc * 8);
    }
}

// ---------------- final: asp_wn, proj x2, logits, label copy (fp32) ----------------------
__global__ __launch_bounds__(256) void final_kernel(const float* __restrict__ ofp,
                                                    const float* __restrict__ ofc_raw,
                                                    const float* __restrict__ aspect,
                                                    const float* __restrict__ pooled,
                                                    const float* __restrict__ fpdW,
                                                    const float* __restrict__ fpdb,
                                                    const float* __restrict__ fcdW,
                                                    const float* __restrict__ fcdb,
                                                    float* __restrict__ out) {
    __shared__ float red[256];
    __shared__ float fp[Dn], fc[Dn], fy[Dn];
    int b = blockIdx.x, t = threadIdx.x;
    float awv = aspect[(long)b * Sn + t] + aspect[(long)b * Sn + t + 256];
    float asp_wn = brsum(awv, red);
    for (int i = t; i < Dn; i += 256) {
        fp[i] = ofp[(long)b * Dn + i];
        fc[i] = ofc_raw[(long)b * Dn + i] / asp_wn;
    }
    __syncthreads();
    float p0 = 0.0f, p1 = 0.0f;
    for (int i = t; i < Dn; i += 256) { p0 += fc[i] * fc[i]; p1 += fp[i] * fc[i]; }
    float dfc2 = brsum(p0, red);
    float dfpfc = brsum(p1, red);
    float bmo = sqrtf(dfc2);
    float coef = dfpfc / bmo;
    float bden = fmaxf(bmo, 1e-12f);
    float q0 = 0.0f, q1 = 0.0f;
    for (int i = t; i < Dn; i += 256) {
        float tv = fp[i] - coef * fc[i] / bden;
        fy[i] = tv;
        q0 += tv * tv;
        q1 += fp[i] * tv;
    }
    float dt2 = brsum(q0, red);
    float dfpt = brsum(q1, red);
    float tmo = sqrtf(dt2);
    float coef2 = dfpt / tmo;
    float tden = fmaxf(tmo, 1e-12f);
    for (int i = t; i < Dn; i += 256) fy[i] = coef2 * fy[i] / tden;
    __syncthreads();
    for (int i = t; i < Dn; i += 256) out[2 * Bn * Pn + (long)b * Dn + i] = fy[i];
    for (int i = t; i < Dn; i += 256)
        out[2 * Bn * Pn + Bn * Dn + (long)b * Dn + i] = pooled[(long)b * Dn + i];
    for (int j = 0; j < Pn; j++) {
        float lp = 0.0f, lc = 0.0f;
        for (int i = t; i < Dn; i += 256) {
            lp += fy[i] * fpdW[(long)j * Dn + i];
            lc += fc[i] * fcdW[(long)j * Dn + i];
        }
        float rp = brsum(lp, red);
        float rc = brsum(lc, red);
        if (t == 0) {
            out[(long)b * Pn + j] = rp + fpdb[j];
            out[Bn * Pn + (long)b * Pn + j] = rc + fcdb[j];
        }
    }
}

// ---------------- host orchestration ----------------
extern "C" void kernel_launch(void* const* d_in, const int* in_sizes, int n_in,
                              void* d_out, int out_size, void* d_ws, size_t ws_size,
                              hipStream_t stream) {
    const float* seq     = (const float*)d_in[0];
    const float* pooled  = (const float*)d_in[1];
    const int*   src_msk = (const int*)d_in[2];
    const float* aspect  = (const float*)d_in[3];
    const float* ln_a    = (const float*)d_in[4];
    const float* ln_b    = (const float*)d_in[5];
    float* out = (float*)d_out;

    const long NTD = (long)Bn * Sn * Dn;   // 12,582,912
    const long NSS = (long)Bn * Sn * Sn;   // 8,388,608
    const long DD  = (long)Dn * Dn;        // 589,824
    const long SD  = (long)Sn * Dn;        // 393,216

    char* w = (char*)d_ws;
    bf16_t* xbf   = (bf16_t*)w;            // NTD
    bf16_t* QK    = xbf + NTD;             // [B][S][3072] = 4*NTD
    bf16_t* H1    = QK;                    // [2][32][512][768] = 2*NTD (after fused_adj)
    bf16_t* XT    = QK + 2 * NTD;          // [2][32][768][512] = 2*NTD (after fused_adj)
    bf16_t* adjb  = QK + 4 * NTD;          // [2][32][512][512] = 2*NSS
    float*  denom = (float*)(adjb + 2 * NSS);   // [2][32][512] f32
    float*  ofp   = denom + 2L * Bn * Sn;       // [2][32][768] f32 (ofp then ofc)
    float*  bcat  = ofp + 2L * Bn * Dn;         // 8*768 f32
    bf16_t* Wb    = (bf16_t*)(bcat + 8 * Dn);   // 8*DD

    ln_kernel<<<dim3(Bn * Sn), dim3(256), 0, stream>>>(seq, ln_a, ln_b, xbf);
    zero_kernel<<<dim3((2 * Bn * Dn + 255) / 256), dim3(256), 0, stream>>>(ofp, 2 * Bn * Dn);

    // weights: [0]Wq_fp [1]Wk_fp [2]Wq_fc [3]Wk_fc [4]W0_fp [5]W0_fc [6]W1_fp [7]W1_fc
    cvt8<<<dim3(576, 8), dim3(256), 0, stream>>>(
        (const float*)d_in[6], (const float*)d_in[8],
        (const float*)d_in[14], (const float*)d_in[16],
        (const float*)d_in[10], (const float*)d_in[18],
        (const float*)d_in[12], (const float*)d_in[20], Wb);
    // biases: [bq_fp|bk_fp|bq_fc|bk_fc | b0_fp|b0_fc | b1_fp|b1_fc]
    biascat_k<<<dim3(8), dim3(256), 0, stream>>>(
        (const float*)d_in[7], (const float*)d_in[9],
        (const float*)d_in[15], (const float*)d_in[17],
        (const float*)d_in[11], (const float*)d_in[19],
        (const float*)d_in[13], (const float*)d_in[21], bcat);

    // [Q_fp|K_fp|Q_fc|K_fc] = x @ Wqk^T + bias   [M=16384, N=3072, K=768]
    gemm256<0><<<dim3(24, 64, 1), dim3(512), 0, stream>>>(
        xbf, Wb, QK, nullptr, Dn, Dn, 3072, Dn,
        0, 0, 0, 0, 0, 0, 0, bcat, 0, nullptr, nullptr);

    // adj (both branches) = mean_h softmax(mask(Q K^T/sqrt(dk))) + diag/rowmask/denom
    fused_adj<<<dim3(2 * Bn * Sn / 32), dim3(256), 0, stream>>>(QK, adjb, denom, src_msk);

    // XW0T = W0_br @ x_b^T   [M=768,N=512,K=768], z = br*32+b
    gemm_bt<0><<<dim3(4, 6, 64), dim3(256), 0, stream>>>(
        Wb + 4 * DD, xbf, XT, nullptr, Dn, Dn, Sn, Dn,
        DD, 0, 0, SD, 32 * SD, SD,
        5, 1.0f, nullptr, 0, nullptr, nullptr);

    // H1 = relu((adj @ XW0 + b0)/denom)   [M=512,N=768,K=512]
    gemm_bt<1><<<dim3(6, 4, 64), dim3(256), 0, stream>>>(
        adjb, XT, H1, nullptr, Sn, Sn, Dn, Sn,
        32L * Sn * Sn, (long)Sn * Sn, 32 * SD, SD, 32 * SD, SD,
        5, 1.0f, bcat + 4 * Dn, Dn, denom, nullptr);

    // H1W1T = W1_br @ H1^T   [M=768,N=512,K=768]
    gemm_bt<0><<<dim3(4, 6, 64), dim3(256), 0, stream>>>(
        Wb + 6 * DD, H1, XT, nullptr, Dn, Dn, Sn, Dn,
        DD, 0, 32 * SD, SD, 32 * SD, SD,
        5, 1.0f, nullptr, 0, nullptr, nullptr);

    // H2 fused: outv[z,n] += sum_m w(m)*relu((adj@H1W1 + b1)/denom)
    gemm_bt<2><<<dim3(6, 4, 64), dim3(256), 0, stream>>>(
        adjb, XT, nullptr, ofp, Sn, Sn, 0, Sn,
        32L * Sn * Sn, (long)Sn * Sn, 32 * SD, SD, 0, 0,
        5, 1.0f, bcat + 6 * Dn, Dn, denom, aspect);

    final_kernel<<<dim3(Bn), dim3(256), 0, stream>>>(
        ofp, ofp + (long)Bn * Dn, aspect, pooled,
        (const float*)d_in[22], (const float*)d_in[23],
        (const float*)d_in[24], (const float*)d_in[25], out);
}

// Round 17
// 497.647 us; speedup vs baseline: 1.1251x; 1.1251x over previous
//
#include <hip/hip_runtime.h>
#include <math.h>
#include <stdint.h>

#define Bn 32
#define Sn 512
#define Dn 768
#define Hn 8
#define DKn 96
#define Pn 3

typedef __bf16 bf16_t;
typedef bf16_t bf16x8 __attribute__((ext_vector_type(8)));
typedef float f32x4 __attribute__((ext_vector_type(4)));

__device__ __forceinline__ bf16_t f2bf(float f) { return (bf16_t)f; }

__device__ __forceinline__ void gload16(const void* g, void* l) {
    __builtin_amdgcn_global_load_lds((const __attribute__((address_space(1))) void*)g,
                                     (__attribute__((address_space(3))) void*)l, 16, 0, 0);
}

// ---------------- block reduction helpers (blockDim == 256) ----------------
__device__ __forceinline__ float brsum(float v, float* red) {
    int t = threadIdx.x;
    red[t] = v; __syncthreads();
    #pragma unroll
    for (int o = 128; o > 0; o >>= 1) {
        if (t < o) red[t] += red[t + o];
        __syncthreads();
    }
    float r = red[0]; __syncthreads();
    return r;
}

// ---------------- LayerNorm -> bf16 (torch-style: unbiased var, eps on std) -------------
__global__ __launch_bounds__(256) void ln_kernel(const float* __restrict__ in,
                                                 const float* __restrict__ ga,
                                                 const float* __restrict__ gb,
                                                 bf16_t* __restrict__ out) {
    __shared__ float red[256];
    long row = blockIdx.x;
    const float* x = in + row * Dn;
    bf16_t* y = out + row * Dn;
    int t = threadIdx.x;
    float v0 = x[t], v1 = x[t + 256], v2 = x[t + 512];
    float mean = brsum(v0 + v1 + v2, red) / (float)Dn;
    float d0 = v0 - mean, d1 = v1 - mean, d2 = v2 - mean;
    float ss = brsum(d0 * d0 + d1 * d1 + d2 * d2, red);
    float inv = 1.0f / (sqrtf(ss / (float)(Dn - 1)) + 1e-6f);
    y[t]       = f2bf(ga[t]       * d0 * inv + gb[t]);
    y[t + 256] = f2bf(ga[t + 256] * d1 * inv + gb[t + 256]);
    y[t + 512] = f2bf(ga[t + 512] * d2 * inv + gb[t + 512]);
}

// ---------------- fp32 -> bf16 weight conversion (8 matrices of Dn x Dn) -----------------
__global__ __launch_bounds__(256) void cvt8(const float* __restrict__ s0,
                                            const float* __restrict__ s1,
                                            const float* __restrict__ s2,
                                            const float* __restrict__ s3,
                                            const float* __restrict__ s4,
                                            const float* __restrict__ s5,
                                            const float* __restrict__ s6,
                                            const float* __restrict__ s7,
                                            bf16_t* __restrict__ dst) {
    int y = blockIdx.y;
    const float* s = (y == 0) ? s0 : (y == 1) ? s1 : (y == 2) ? s2 : (y == 3) ? s3
                   : (y == 4) ? s4 : (y == 5) ? s5 : (y == 6) ? s6 : s7;
    long i = (long)blockIdx.x * 1024 + threadIdx.x * 4;
    float4 v = *reinterpret_cast<const float4*>(s + i);
    bf16_t* d = dst + (long)y * Dn * Dn + i;
    d[0] = f2bf(v.x); d[1] = f2bf(v.y); d[2] = f2bf(v.z); d[3] = f2bf(v.w);
}

// ---------------- bias concat: 8 segments of 768 floats ----------------
__global__ __launch_bounds__(256) void biascat_k(const float* __restrict__ s0,
                                                 const float* __restrict__ s1,
                                                 const float* __restrict__ s2,
                                                 const float* __restrict__ s3,
                                                 const float* __restrict__ s4,
                                                 const float* __restrict__ s5,
                                                 const float* __restrict__ s6,
                                                 const float* __restrict__ s7,
                                                 float* __restrict__ dst) {
    int y = blockIdx.x;
    const float* s = (y == 0) ? s0 : (y == 1) ? s1 : (y == 2) ? s2 : (y == 3) ? s3
                   : (y == 4) ? s4 : (y == 5) ? s5 : (y == 6) ? s6 : s7;
    for (int i = threadIdx.x; i < Dn; i += 256) dst[(long)y * Dn + i] = s[i];
}

__global__ void zero_kernel(float* p, int n) {
    int i = blockIdx.x * 256 + threadIdx.x;
    if (i < n) p[i] = 0.0f;
}

// =========================================================================================
// gemm_bt: bf16 MFMA NT GEMM, 128x128 tile, 4 waves, BK=32, global_load_lds staging.
// (R15-proven layout: row-major granules -> 64B-contiguous per 4-lane group on the global
// side; the 8-way LDS read conflict is NOT on the 2-phase critical path — R16 A/B.)
// =========================================================================================
template <int EPI>
__global__ __launch_bounds__(256) void gemm_bt(
    const bf16_t* __restrict__ Ag, const bf16_t* __restrict__ Bg,
    bf16_t* __restrict__ Cg, float* __restrict__ outv,
    int lda, int ldb, int ldc, int K,
    long sAhi, long sAlo, long sBhi, long sBlo, long sChi, long sClo,
    int lgZ, float alpha,
    const float* __restrict__ bias, long bias_zs,
    const float* __restrict__ denom,
    const float* __restrict__ aspw) {
    __shared__ __align__(16) bf16_t As[128 * 32];
    __shared__ __align__(16) bf16_t Bs[128 * 32];

    unsigned gx = gridDim.x, gy = gridDim.y;
    unsigned nwg = gx * gy * gridDim.z;
    unsigned flat = (blockIdx.z * gy + blockIdx.y) * gx + blockIdx.x;
    unsigned q8 = nwg >> 3, r8 = nwg & 7;
    unsigned xcd = flat & 7, idx = flat >> 3;
    unsigned swz = (xcd < r8 ? xcd * (q8 + 1) : r8 * (q8 + 1) + (xcd - r8) * q8) + idx;
    unsigned bx = swz % gx;
    unsigned rest = swz / gx;
    unsigned by = rest % gy;
    unsigned zz = rest / gy;
    int zb = zz >> lgZ;
    int zg = zz & ((1 << lgZ) - 1);
    long zful = zz;

    const bf16_t* A = Ag + zb * sAhi + zg * sAlo;
    const bf16_t* B = Bg + zb * sBhi + zg * sBlo;

    int n0 = bx * 128;
    int m0 = by * 128;
    int tid = threadIdx.x;
    int lane = tid & 63, wv = tid >> 6;
    int wm = wv >> 1, wn = wv & 1;

    int sub = lane >> 2;
    int kcol = (lane & 3) * 8;
    const bf16_t* pA0 = A + (size_t)(m0 + wv * 16 + sub) * lda + kcol;
    const bf16_t* pA1 = pA0 + (size_t)64 * lda;
    const bf16_t* pB0 = B + (size_t)(n0 + wv * 16 + sub) * ldb + kcol;
    const bf16_t* pB1 = pB0 + (size_t)64 * ldb;
    bf16_t* lA0 = As + wv * 512 + lane * 8;
    bf16_t* lA1 = As + (4 + wv) * 512 + lane * 8;
    bf16_t* lB0 = Bs + wv * 512 + lane * 8;
    bf16_t* lB1 = Bs + (4 + wv) * 512 + lane * 8;

    f32x4 acc[4][4];
    #pragma unroll
    for (int i = 0; i < 4; i++)
        #pragma unroll
        for (int j = 0; j < 4; j++) acc[i][j] = (f32x4){0.f, 0.f, 0.f, 0.f};

    const bf16_t* ar = As + (wm * 64 + (lane & 15)) * 32 + (lane >> 4) * 8;
    const bf16_t* br = Bs + (wn * 64 + (lane & 15)) * 32 + (lane >> 4) * 8;

    for (int k0 = 0; k0 < K; k0 += 32) {
        gload16(pA0 + k0, lA0);
        gload16(pA1 + k0, lA1);
        gload16(pB0 + k0, lB0);
        gload16(pB1 + k0, lB1);
        __syncthreads();
        bf16x8 a[4], b[4];
        #pragma unroll
        for (int i = 0; i < 4; i++) a[i] = *(const bf16x8*)(ar + i * 16 * 32);
        #pragma unroll
        for (int j = 0; j < 4; j++) b[j] = *(const bf16x8*)(br + j * 16 * 32);
        #pragma unroll
        for (int i = 0; i < 4; i++)
            #pragma unroll
            for (int j = 0; j < 4; j++)
                acc[i][j] = __builtin_amdgcn_mfma_f32_16x16x32_bf16(a[i], b[j], acc[i][j], 0, 0, 0);
        __syncthreads();
    }

    int nb = n0 + wn * 64 + (lane & 15);
    int mbase = m0 + wm * 64 + (lane >> 4) * 4;
    const float* bz = bias ? bias + zb * bias_zs : nullptr;

    if (EPI == 0) {
        bf16_t* Cz = Cg + zb * sChi + zg * sClo;
        #pragma unroll
        for (int i = 0; i < 4; i++) {
            #pragma unroll
            for (int r = 0; r < 4; r++) {
                long m = mbase + i * 16 + r;
                bf16_t* crow = Cz + m * (long)ldc;
                #pragma unroll
                for (int j = 0; j < 4; j++) {
                    int col = nb + j * 16;
                    float v = acc[i][j][r] * alpha;
                    if (bz) v += bz[col];
                    crow[col] = f2bf(v);
                }
            }
        }
    } else if (EPI == 1) {
        bf16_t* Cz = Cg + zb * sChi + zg * sClo;
        const float* dz = denom + zful * Sn;
        #pragma unroll
        for (int i = 0; i < 4; i++) {
            #pragma unroll
            for (int r = 0; r < 4; r++) {
                int m = mbase + i * 16 + r;
                float dinv = 1.0f / dz[m];
                bf16_t* crow = Cz + (long)m * ldc;
                #pragma unroll
                for (int j = 0; j < 4; j++) {
                    float v = fmaxf((acc[i][j][r] + bz[nb + j * 16]) * dinv, 0.0f);
                    crow[nb + j * 16] = f2bf(v);
                }
            }
        }
    } else {  // EPI == 2
        const float* dz = denom + zful * Sn;
        float csum[4] = {0.f, 0.f, 0.f, 0.f};
        #pragma unroll
        for (int i = 0; i < 4; i++) {
            #pragma unroll
            for (int r = 0; r < 4; r++) {
                int m = mbase + i * 16 + r;
                float dinv = 1.0f / dz[m];
                float wgt = (aspw && zb) ? aspw[(long)zg * Sn + m] : 1.0f;
                #pragma unroll
                for (int j = 0; j < 4; j++) {
                    float v = fmaxf((acc[i][j][r] + bz[nb + j * 16]) * dinv, 0.0f);
                    csum[j] += v * wgt;
                }
            }
        }
        #pragma unroll
        for (int j = 0; j < 4; j++) {
            float s = csum[j];
            s += __shfl_xor(s, 16);
            s += __shfl_xor(s, 32);
            if (lane < 16) atomicAdd(&outv[zful * Dn + nb + j * 16], s);
        }
    }
}

// =========================================================================================
// gemm256: 256x128 tile, BK=32, 8 waves (4m x 2n, wave-tile 64x64, acc 4x4 = 64 regs),
// 3-buffer LDS (72 KB) with 2-tile-ahead staging and counted vmcnt(3); 2 blocks/CU.
// =========================================================================================
#define CH 24   // 16 A-chunks + 8 B-chunks, each 512 elems (16 rows x 32 k)
template <int EPI>
__global__ __launch_bounds__(512, 4) void gemm256(
    const bf16_t* __restrict__ Ag, const bf16_t* __restrict__ Bg,
    bf16_t* __restrict__ Cg, float* __restrict__ outv,
    int lda, int ldb, int ldc, int K,
    long sAhi, long sAlo, long sBhi, long sBlo, long sChi, long sClo,
    int lgZ,
    const float* __restrict__ bias, long bias_zs,
    const float* __restrict__ denom,
    const float* __restrict__ aspw) {
    __shared__ __align__(16) bf16_t lds[3][CH * 512];   // 72 KiB

    unsigned gx = gridDim.x, gy = gridDim.y;
    unsigned nwg = gx * gy * gridDim.z;
    unsigned flat = (blockIdx.z * gy + blockIdx.y) * gx + blockIdx.x;
    unsigned q8 = nwg >> 3, r8 = nwg & 7;
    unsigned xcd = flat & 7, idx = flat >> 3;
    unsigned swz = (xcd < r8 ? xcd * (q8 + 1) : r8 * (q8 + 1) + (xcd - r8) * q8) + idx;
    unsigned bx = swz % gx;
    unsigned rest = swz / gx;
    unsigned by = rest % gy;
    unsigned zz = rest / gy;
    int zb = zz >> lgZ;
    int zg = zz & ((1 << lgZ) - 1);
    long zful = zz;

    const bf16_t* A = Ag + zb * sAhi + zg * sAlo;
    const bf16_t* B = Bg + zb * sBhi + zg * sBlo;

    int n0 = bx * 128, m0 = by * 256;
    int tid = threadIdx.x;
    int lane = tid & 63, w = tid >> 6;
    int wm = w >> 1, wn = w & 1;

    const int NT = K >> 5;

    int srowl = lane & 15;
    int skc = (lane >> 4) * 8;
    const bf16_t* src[3];
    int loff[3];
    #pragma unroll
    for (int p = 0; p < 3; ++p) {
        int ch = w * 3 + p;
        src[p] = (ch < 16) ? (A + (size_t)(m0 + ch * 16 + srowl) * lda + skc)
                           : (B + (size_t)(n0 + (ch - 16) * 16 + srowl) * ldb + skc);
        loff[p] = ch * 512 + lane * 8;
    }

    f32x4 acc[4][4];
    #pragma unroll
    for (int i = 0; i < 4; ++i)
        #pragma unroll
        for (int j = 0; j < 4; ++j) acc[i][j] = (f32x4){0.f, 0.f, 0.f, 0.f};

    #pragma unroll
    for (int p = 0; p < 3; ++p) gload16(src[p], &lds[0][loff[p]]);
    if (NT > 1) {
        #pragma unroll
        for (int p = 0; p < 3; ++p) gload16(src[p] + 32, &lds[1][loff[p]]);
        asm volatile("s_waitcnt vmcnt(3)" ::: "memory");
    } else {
        asm volatile("s_waitcnt vmcnt(0)" ::: "memory");
    }
    __builtin_amdgcn_s_barrier();

    int aoff = (wm * 4) * 512 + lane * 8;
    int boff = (16 + wn * 4) * 512 + lane * 8;

    for (int t = 0; t < NT; ++t) {
        const bf16_t* buf = &lds[t % 3][0];
        if (t + 2 < NT) {
            bf16_t* dst = &lds[(t + 2) % 3][0];
            #pragma unroll
            for (int p = 0; p < 3; ++p) gload16(src[p] + (t + 2) * 32, dst + loff[p]);
        }
        bf16x8 a[4], b[4];
        #pragma unroll
        for (int i = 0; i < 4; ++i) a[i] = *(const bf16x8*)(buf + aoff + i * 512);
        #pragma unroll
        for (int j = 0; j < 4; ++j) b[j] = *(const bf16x8*)(buf + boff + j * 512);
        asm volatile("s_waitcnt lgkmcnt(0)" ::: "memory");
        __builtin_amdgcn_sched_barrier(0);
        __builtin_amdgcn_s_setprio(1);
        #pragma unroll
        for (int i = 0; i < 4; ++i)
            #pragma unroll
            for (int j = 0; j < 4; ++j)
                acc[i][j] = __builtin_amdgcn_mfma_f32_16x16x32_bf16(a[i], b[j], acc[i][j], 0, 0, 0);
        __builtin_amdgcn_s_setprio(0);
        if (t + 2 < NT) asm volatile("s_waitcnt vmcnt(3)" ::: "memory");
        else            asm volatile("s_waitcnt vmcnt(0)" ::: "memory");
        __builtin_amdgcn_s_barrier();
    }

    int nb = n0 + wn * 64 + (lane & 15);
    int mbase = m0 + wm * 64 + (lane >> 4) * 4;
    const float* bz = bias ? bias + zb * bias_zs : nullptr;

    if (EPI == 0) {
        bf16_t* Cz = Cg + zb * sChi + zg * sClo;
        #pragma unroll
        for (int i = 0; i < 4; ++i) {
            #pragma unroll
            for (int r = 0; r < 4; ++r) {
                long m = mbase + i * 16 + r;
                bf16_t* crow = Cz + m * (long)ldc;
                #pragma unroll
                for (int j = 0; j < 4; ++j) {
                    int col = nb + j * 16;
                    float v = acc[i][j][r];
                    if (bz) v += bz[col];
                    crow[col] = f2bf(v);
                }
            }
        }
    }
}

// =========================================================================================
// fused_adj (v2 + pad100): adj = mean_h softmax(mask(Q_h K_h^T/sqrt(dk))) + diag/mask/denom
// =========================================================================================
#define KPAD 100
__global__ __launch_bounds__(256) void fused_adj(
    const bf16_t* __restrict__ QK, bf16_t* __restrict__ adjb,
    float* __restrict__ denomv, const int* __restrict__ mask) {
    __shared__ __align__(16) bf16_t Ks[2][128 * KPAD];
    __shared__ float red[4][16];

    int L = blockIdx.x;
    int swzi = (L & 7) * 128 + (L >> 3);   // 1024 blocks, 8 XCDs x 128
    int brc = swzi >> 9;
    int rem = swzi & 511;
    int b = rem >> 4;
    int q0 = (rem & 15) * 32;

    int tid = threadIdx.x;
    int lane = tid & 63, w = tid >> 6;
    int mt = w >> 1, nh = w & 1;
    int g = lane >> 4, c = lane & 15;

    const int LDQ = 3072;
    const bf16_t* Qrow  = QK + ((long)b * Sn + q0 + mt * 16 + c) * LDQ + brc * 1536;
    const bf16_t* Kbase = QK + (long)b * Sn * LDQ + brc * 1536 + Dn;

    const int* mrow = mask + (long)b * Sn;
    unsigned mbits = 0;
    #pragma unroll
    for (int t = 0; t < 4; ++t)
        #pragma unroll
        for (int nj = 0; nj < 4; ++nj)
            if (mrow[t * 128 + nh * 64 + nj * 16 + c] != 0) mbits |= 1u << (t * 4 + nj);

    int srow[6], scc[6];
    #pragma unroll
    for (int p = 0; p < 6; ++p) { int gr = tid + p * 256; srow[p] = gr / 12; scc[p] = gr % 12; }

    f32x4 adjacc[4][4];
    #pragma unroll
    for (int t = 0; t < 4; ++t)
        #pragma unroll
        for (int nj = 0; nj < 4; ++nj) adjacc[t][nj] = (f32x4){0.f, 0.f, 0.f, 0.f};

    f32x4 S[4][4];
    bf16x8 kr0[6], kr1[6], aq[3], aqn[3];
    const float sal = 0.102062072615966f;  // 1/sqrt(96)

    // prologue: tile0 -> kr0 -> Ks[0]; tile1 -> kr1; Q head 0 -> aq
    #pragma unroll
    for (int p = 0; p < 6; ++p)
        kr0[p] = *(const bf16x8*)(Kbase + (long)srow[p] * LDQ + scc[p] * 8);
    #pragma unroll
    for (int ks = 0; ks < 3; ++ks)
        aq[ks] = *(const bf16x8*)(Qrow + ks * 32 + g * 8);
    #pragma unroll
    for (int p = 0; p < 6; ++p)
        *(bf16x8*)(&Ks[0][srow[p] * KPAD + scc[p] * 8]) = kr0[p];
    #pragma unroll
    for (int p = 0; p < 6; ++p)
        kr1[p] = *(const bf16x8*)(Kbase + (long)(128 + srow[p]) * LDQ + scc[p] * 8);
    __syncthreads();

    for (int h = 0; h < Hn; ++h) {
        #pragma unroll
        for (int t = 0; t < 4; ++t)
            #pragma unroll
            for (int nj = 0; nj < 4; ++nj) S[t][nj] = (f32x4){0.f, 0.f, 0.f, 0.f};

        float rs[4];
        #pragma unroll
        for (int t = 0; t < 4; ++t) {
            int it = h * 4 + t;
            if (it + 2 < 32) {
                int nt = it + 2;
                const bf16_t* kp = Kbase + (long)((nt & 3) * 128) * LDQ + (nt >> 2) * 96;
                if ((t & 1) == 0) {
                    #pragma unroll
                    for (int p = 0; p < 6; ++p)
                        kr0[p] = *(const bf16x8*)(kp + (long)srow[p] * LDQ + scc[p] * 8);
                } else {
                    #pragma unroll
                    for (int p = 0; p < 6; ++p)
                        kr1[p] = *(const bf16x8*)(kp + (long)srow[p] * LDQ + scc[p] * 8);
                }
            }
            if (t == 2 && h < 7) {
                #pragma unroll
                for (int ks = 0; ks < 3; ++ks)
                    aqn[ks] = *(const bf16x8*)(Qrow + (h + 1) * 96 + ks * 32 + g * 8);
            }
            #pragma unroll
            for (int nj = 0; nj < 4; ++nj) {
                #pragma unroll
                for (int ks = 0; ks < 3; ++ks) {
                    bf16x8 bk = *(const bf16x8*)(&Ks[t & 1][(nh * 64 + nj * 16 + c) * KPAD + ks * 32 + g * 8]);
                    S[t][nj] = __builtin_amdgcn_mfma_f32_16x16x32_bf16(aq[ks], bk, S[t][nj], 0, 0, 0);
                }
            }
            if (t == 3) {
                rs[0] = rs[1] = rs[2] = rs[3] = 0.f;
                #pragma unroll
                for (int tt = 0; tt < 4; ++tt)
                    #pragma unroll
                    for (int nj = 0; nj < 4; ++nj) {
                        float mkf = ((mbits >> (tt * 4 + nj)) & 1u) ? 1.0f : 0.0f;
                        #pragma unroll
                        for (int ri = 0; ri < 4; ++ri) {
                            float e = mkf * __expf(S[tt][nj][ri] * sal);
                            S[tt][nj][ri] = e;
                            rs[ri] += e;
                        }
                    }
                #pragma unroll
                for (int ri = 0; ri < 4; ++ri) {
                    rs[ri] += __shfl_xor(rs[ri], 1);
                    rs[ri] += __shfl_xor(rs[ri], 2);
                    rs[ri] += __shfl_xor(rs[ri], 4);
                    rs[ri] += __shfl_xor(rs[ri], 8);
                }
                if (c == 0) {
                    #pragma unroll
                    for (int ri = 0; ri < 4; ++ri) red[w][g * 4 + ri] = rs[ri];
                }
            }
            if (it + 1 < 32) {
                if ((t & 1) == 0) {
                    #pragma unroll
                    for (int p = 0; p < 6; ++p)
                        *(bf16x8*)(&Ks[1][srow[p] * KPAD + scc[p] * 8]) = kr1[p];
                } else {
                    #pragma unroll
                    for (int p = 0; p < 6; ++p)
                        *(bf16x8*)(&Ks[0][srow[p] * KPAD + scc[p] * 8]) = kr0[p];
                }
            }
            __syncthreads();
            if (t == 3) {
                float inv[4];
                #pragma unroll
                for (int ri = 0; ri < 4; ++ri)
                    inv[ri] = 0.125f / (red[w][g * 4 + ri] + red[w ^ 1][g * 4 + ri]);
                #pragma unroll
                for (int tt = 0; tt < 4; ++tt)
                    #pragma unroll
                    for (int nj = 0; nj < 4; ++nj)
                        #pragma unroll
                        for (int ri = 0; ri < 4; ++ri)
                            adjacc[tt][nj][ri] += S[tt][nj][ri] * inv[ri];
                if (h < 7) {
                    #pragma unroll
                    for (int ks = 0; ks < 3; ++ks) aq[ks] = aqn[ks];
                }
            }
        }
    }

    // finalize: diag=1, row-mask, rowsum -> denom
    float rm[4];
    #pragma unroll
    for (int ri = 0; ri < 4; ++ri)
        rm[ri] = (mrow[q0 + mt * 16 + g * 4 + ri] != 0) ? 1.0f : 0.0f;
    float rs2[4] = {0.f, 0.f, 0.f, 0.f};
    #pragma unroll
    for (int t = 0; t < 4; ++t)
        #pragma unroll
        for (int nj = 0; nj < 4; ++nj) {
            int n = t * 128 + nh * 64 + nj * 16 + c;
            #pragma unroll
            for (int ri = 0; ri < 4; ++ri) {
                float v = adjacc[t][nj][ri];
                int q = q0 + mt * 16 + g * 4 + ri;
                if (n == q) v = 1.0f;
                v *= rm[ri];
                adjacc[t][nj][ri] = v;
                rs2[ri] += v;
            }
        }
    #pragma unroll
    for (int ri = 0; ri < 4; ++ri) {
        rs2[ri] += __shfl_xor(rs2[ri], 1);
        rs2[ri] += __shfl_xor(rs2[ri], 2);
        rs2[ri] += __shfl_xor(rs2[ri], 4);
        rs2[ri] += __shfl_xor(rs2[ri], 8);
    }
    __syncthreads();   // all part-2 red reads done before overwrite (WAR)
    if (c == 0) {
        #pragma unroll
        for (int ri = 0; ri < 4; ++ri) red[w][g * 4 + ri] = rs2[ri];
    }
    __syncthreads();
    long zful = (long)brc * Bn + b;
    if (nh == 0 && c == 0) {
        #pragma unroll
        for (int ri = 0; ri < 4; ++ri)
            denomv[zful * Sn + q0 + mt * 16 + g * 4 + ri] =
                red[w][g * 4 + ri] + red[w ^ 1][g * 4 + ri] + 1.0f;
    }
    // stage adj tile (reuse Ks) as bf16 [32][520], then coalesced write
    bf16_t* stg = &Ks[0][0];
    #pragma unroll
    for (int t = 0; t < 4; ++t)
        #pragma unroll
        for (int nj = 0; nj < 4; ++nj) {
            int n = t * 128 + nh * 64 + nj * 16 + c;
            #pragma unroll
            for (int ri = 0; ri < 4; ++ri)
                stg[(mt * 16 + g * 4 + ri) * 520 + n] = f2bf(adjacc[t][nj][ri]);
        }
    __syncthreads();
    bf16_t* arow = adjb + (zful * Sn + q0) * Sn;
    #pragma unroll
    for (int p = 0; p < 8; ++p) {
        int gr = tid + p * 256;
        int row = gr >> 6, cc = gr & 63;
        *(bf16x8*)(arow + (long)row * Sn + cc * 8) = *(const bf16x8*)(stg + row * 520 + cc * 8);
    }
}

// ---------------- final: asp_wn, proj x2, logits, label copy (fp32) ----------------------
__global__ __launch_bounds__(256) void final_kernel(const float* __restrict__ ofp,
                                                    const float* __restrict__ ofc_raw,
                                                    const float* __restrict__ aspect,
                                                    const float* __restrict__ pooled,
                                                    const float* __restrict__ fpdW,
                                                    const float* __restrict__ fpdb,
                                                    const float* __restrict__ fcdW,
                                                    const float* __restrict__ fcdb,
                                                    float* __restrict__ out) {
    __shared__ float red[256];
    __shared__ float fp[Dn], fc[Dn], fy[Dn];
    int b = blockIdx.x, t = threadIdx.x;
    float awv = aspect[(long)b * Sn + t] + aspect[(long)b * Sn + t + 256];
    float asp_wn = brsum(awv, red);
    for (int i = t; i < Dn; i += 256) {
        fp[i] = ofp[(long)b * Dn + i];
        fc[i] = ofc_raw[(long)b * Dn + i] / asp_wn;
    }
    __syncthreads();
    float p0 = 0.0f, p1 = 0.0f;
    for (int i = t; i < Dn; i += 256) { p0 += fc[i] * fc[i]; p1 += fp[i] * fc[i]; }
    float dfc2 = brsum(p0, red);
    float dfpfc = brsum(p1, red);
    float bmo = sqrtf(dfc2);
    float coef = dfpfc / bmo;
    float bden = fmaxf(bmo, 1e-12f);
    float q0 = 0.0f, q1 = 0.0f;
    for (int i = t; i < Dn; i += 256) {
        float tv = fp[i] - coef * fc[i] / bden;
        fy[i] = tv;
        q0 += tv * tv;
        q1 += fp[i] * tv;
    }
    float dt2 = brsum(q0, red);
    float dfpt = brsum(q1, red);
    float tmo = sqrtf(dt2);
    float coef2 = dfpt / tmo;
    float tden = fmaxf(tmo, 1e-12f);
    for (int i = t; i < Dn; i += 256) fy[i] = coef2 * fy[i] / tden;
    __syncthreads();
    for (int i = t; i < Dn; i += 256) out[2 * Bn * Pn + (long)b * Dn + i] = fy[i];
    for (int i = t; i < Dn; i += 256)
        out[2 * Bn * Pn + Bn * Dn + (long)b * Dn + i] = pooled[(long)b * Dn + i];
    for (int j = 0; j < Pn; j++) {
        float lp = 0.0f, lc = 0.0f;
        for (int i = t; i < Dn; i += 256) {
            lp += fy[i] * fpdW[(long)j * Dn + i];
            lc += fc[i] * fcdW[(long)j * Dn + i];
        }
        float rp = brsum(lp, red);
        float rc = brsum(lc, red);
        if (t == 0) {
            out[(long)b * Pn + j] = rp + fpdb[j];
            out[Bn * Pn + (long)b * Pn + j] = rc + fcdb[j];
        }
    }
}

// ---------------- host orchestration ----------------
extern "C" void kernel_launch(void* const* d_in, const int* in_sizes, int n_in,
                              void* d_out, int out_size, void* d_ws, size_t ws_size,
                              hipStream_t stream) {
    const float* seq     = (const float*)d_in[0];
    const float* pooled  = (const float*)d_in[1];
    const int*   src_msk = (const int*)d_in[2];
    const float* aspect  = (const float*)d_in[3];
    const float* ln_a    = (const float*)d_in[4];
    const float* ln_b    = (const float*)d_in[5];
    float* out = (float*)d_out;

    const long NTD = (long)Bn * Sn * Dn;   // 12,582,912
    const long NSS = (long)Bn * Sn * Sn;   // 8,388,608
    const long DD  = (long)Dn * Dn;        // 589,824
    const long SD  = (long)Sn * Dn;        // 393,216

    char* w = (char*)d_ws;
    bf16_t* xbf   = (bf16_t*)w;            // NTD
    bf16_t* QK    = xbf + NTD;             // [B][S][3072] = 4*NTD
    bf16_t* H1    = QK;                    // [2][32][512][768] = 2*NTD (after fused_adj)
    bf16_t* XT    = QK + 2 * NTD;          // [2][32][768][512] = 2*NTD (after fused_adj)
    bf16_t* adjb  = QK + 4 * NTD;          // [2][32][512][512] = 2*NSS
    float*  denom = (float*)(adjb + 2 * NSS);   // [2][32][512] f32
    float*  ofp   = denom + 2L * Bn * Sn;       // [2][32][768] f32 (ofp then ofc)
    float*  bcat  = ofp + 2L * Bn * Dn;         // 8*768 f32
    bf16_t* Wb    = (bf16_t*)(bcat + 8 * Dn);   // 8*DD

    ln_kernel<<<dim3(Bn * Sn), dim3(256), 0, stream>>>(seq, ln_a, ln_b, xbf);
    zero_kernel<<<dim3((2 * Bn * Dn + 255) / 256), dim3(256), 0, stream>>>(ofp, 2 * Bn * Dn);

    // weights: [0]Wq_fp [1]Wk_fp [2]Wq_fc [3]Wk_fc [4]W0_fp [5]W0_fc [6]W1_fp [7]W1_fc
    cvt8<<<dim3(576, 8), dim3(256), 0, stream>>>(
        (const float*)d_in[6], (const float*)d_in[8],
        (const float*)d_in[14], (const float*)d_in[16],
        (const float*)d_in[10], (const float*)d_in[18],
        (const float*)d_in[12], (const float*)d_in[20], Wb);
    // biases: [bq_fp|bk_fp|bq_fc|bk_fc | b0_fp|b0_fc | b1_fp|b1_fc]
    biascat_k<<<dim3(8), dim3(256), 0, stream>>>(
        (const float*)d_in[7], (const float*)d_in[9],
        (const float*)d_in[15], (const float*)d_in[17],
        (const float*)d_in[11], (const float*)d_in[19],
        (const float*)d_in[13], (const float*)d_in[21], bcat);

    // [Q_fp|K_fp|Q_fc|K_fc] = x @ Wqk^T + bias   [M=16384, N=3072, K=768]
    gemm256<0><<<dim3(24, 64, 1), dim3(512), 0, stream>>>(
        xbf, Wb, QK, nullptr, Dn, Dn, 3072, Dn,
        0, 0, 0, 0, 0, 0, 0, bcat, 0, nullptr, nullptr);

    // adj (both branches) = mean_h softmax(mask(Q K^T/sqrt(dk))) + diag/rowmask/denom
    fused_adj<<<dim3(2 * Bn * Sn / 32), dim3(256), 0, stream>>>(QK, adjb, denom, src_msk);

    // XW0T = W0_br @ x_b^T   [M=768,N=512,K=768], z = br*32+b
    gemm_bt<0><<<dim3(4, 6, 64), dim3(256), 0, stream>>>(
        Wb + 4 * DD, xbf, XT, nullptr, Dn, Dn, Sn, Dn,
        DD, 0, 0, SD, 32 * SD, SD,
        5, 1.0f, nullptr, 0, nullptr, nullptr);

    // H1 = relu((adj @ XW0 + b0)/denom)   [M=512,N=768,K=512]
    gemm_bt<1><<<dim3(6, 4, 64), dim3(256), 0, stream>>>(
        adjb, XT, H1, nullptr, Sn, Sn, Dn, Sn,
        32L * Sn * Sn, (long)Sn * Sn, 32 * SD, SD, 32 * SD, SD,
        5, 1.0f, bcat + 4 * Dn, Dn, denom, nullptr);

    // H1W1T = W1_br @ H1^T   [M=768,N=512,K=768]
    gemm_bt<0><<<dim3(4, 6, 64), dim3(256), 0, stream>>>(
        Wb + 6 * DD, H1, XT, nullptr, Dn, Dn, Sn, Dn,
        DD, 0, 32 * SD, SD, 32 * SD, SD,
        5, 1.0f, nullptr, 0, nullptr, nullptr);

    // H2 fused: outv[z,n] += sum_m w(m)*relu((adj@H1W1 + b1)/denom)
    gemm_bt<2><<<dim3(6, 4, 64), dim3(256), 0, stream>>>(
        adjb, XT, nullptr, ofp, Sn, Sn, 0, Sn,
        32L * Sn * Sn, (long)Sn * Sn, 32 * SD, SD, 0, 0,
        5, 1.0f, bcat + 6 * Dn, Dn, denom, aspect);

    final_kernel<<<dim3(Bn), dim3(256), 0, stream>>>(
        ofp, ofp + (long)Bn * Dn, aspect, pooled,
        (const float*)d_in[22], (const float*)d_in[23],
        (const float*)d_in[24], (const float*)d_in[25], out);
}